// Round 1
// baseline (987.741 us; speedup 1.0000x reference)
//
#include <hip/hip_runtime.h>
#include <cstdint>
#include <math.h>

// Problem constants
#define Bsz 4
#define Lsz 1024
#define Dsz 256
#define Hsz 8
#define HD  2048          // H*D
#define NROWS (Bsz*Lsz)   // 4096
#define INV_TEMP 0.0625f  // 1/sqrt(256)

// GEMM tile params: 64x64 tile, BK=16, 256 threads, 4x4 micro-tile
#define BM 64
#define BN 64
#define BK 16

// C[m][n] = alpha * sum_k A[m][k] * (BT ? Bm[n][k] : Bm[k][n])
// Batched over blockIdx.z with 2-level batch index: z = i1*inner_div? (i1 = z/inner, i2 = z%inner)
template <bool BT>
__global__ __launch_bounds__(256) void gemm_tile(
    const float* __restrict__ A, const float* __restrict__ Bm, float* __restrict__ C,
    int M, int N, int K, int lda, int ldb, int ldc,
    int inner,
    long long sA1, long long sA2, long long sB1, long long sB2,
    long long sC1, long long sC2, float alpha)
{
    const int z  = blockIdx.z;
    const int i1 = z / inner;
    const int i2 = z % inner;
    A  += (size_t)i1 * sA1 + (size_t)i2 * sA2;
    Bm += (size_t)i1 * sB1 + (size_t)i2 * sB2;
    C  += (size_t)i1 * sC1 + (size_t)i2 * sC2;

    __shared__ float As[BK][BM];
    __shared__ float Bs[BK][BN];

    const int tid = threadIdx.x;
    const int tx = tid & 15;       // 0..15 -> col group
    const int ty = tid >> 4;       // 0..15 -> row group
    const int m0 = blockIdx.x * BM;
    const int n0 = blockIdx.y * BN;

    // A-style load: thread loads 4 consecutive k of one row
    const int la_m = tid >> 2;        // 0..63
    const int la_k = (tid & 3) * 4;   // 0,4,8,12
    // B-normal load ([K][N]): thread loads 4 consecutive n of one k-row
    const int lb_k = tid >> 4;        // 0..15
    const int lb_n = (tid & 15) * 4;  // 0..60

    float acc[4][4] = {};

    for (int k0 = 0; k0 < K; k0 += BK) {
        // Load A tile (A[m][k], k contiguous)
        {
            const float* p = A + (size_t)(m0 + la_m) * lda + (k0 + la_k);
            float4 v = *(const float4*)p;
            As[la_k + 0][la_m] = v.x;
            As[la_k + 1][la_m] = v.y;
            As[la_k + 2][la_m] = v.z;
            As[la_k + 3][la_m] = v.w;
        }
        if (BT) {
            // Bm[n][k], k contiguous
            const float* p = Bm + (size_t)(n0 + la_m) * ldb + (k0 + la_k);
            float4 v = *(const float4*)p;
            Bs[la_k + 0][la_m] = v.x;
            Bs[la_k + 1][la_m] = v.y;
            Bs[la_k + 2][la_m] = v.z;
            Bs[la_k + 3][la_m] = v.w;
        } else {
            // Bm[k][n], n contiguous
            const float* p = Bm + (size_t)(k0 + lb_k) * ldb + (n0 + lb_n);
            float4 v = *(const float4*)p;
            Bs[lb_k][lb_n + 0] = v.x;
            Bs[lb_k][lb_n + 1] = v.y;
            Bs[lb_k][lb_n + 2] = v.z;
            Bs[lb_k][lb_n + 3] = v.w;
        }
        __syncthreads();

#pragma unroll
        for (int k = 0; k < BK; ++k) {
            float a[4], b[4];
#pragma unroll
            for (int i = 0; i < 4; ++i) a[i] = As[k][ty * 4 + i];
#pragma unroll
            for (int j = 0; j < 4; ++j) b[j] = Bs[k][tx * 4 + j];
#pragma unroll
            for (int i = 0; i < 4; ++i)
#pragma unroll
                for (int j = 0; j < 4; ++j) acc[i][j] += a[i] * b[j];
        }
        __syncthreads();
    }

#pragma unroll
    for (int i = 0; i < 4; ++i) {
        float4 v;
        v.x = acc[i][0] * alpha;
        v.y = acc[i][1] * alpha;
        v.z = acc[i][2] * alpha;
        v.w = acc[i][3] * alpha;
        *(float4*)(C + (size_t)(m0 + ty * 4 + i) * ldc + (n0 + tx * 4)) = v;
    }
}

// ---- masked softmax, in-place on attn rows [H*B, L, L] ----
__global__ __launch_bounds__(256) void softmax_kernel(float* __restrict__ attn,
                                                      const int* __restrict__ mask)
{
    const int r  = blockIdx.x;            // (h*B + b)*L + q
    const int q  = r & (Lsz - 1);
    const int hb = r >> 10;               // h*B + b
    const int b  = hb & (Bsz - 1);
    float* row = attn + (size_t)r * Lsz;
    const int* mrow = mask + ((size_t)(b * Lsz + q)) * Lsz;

    const int t = threadIdx.x;
    float x[4], mv[4];
    float lmax = -1e30f;
#pragma unroll
    for (int i = 0; i < 4; ++i) {
        const int idx = t + i * 256;
        float xv = row[idx];
        float m  = (float)mrow[idx];
        xv = fminf(fmaxf(xv, -15.f), 15.f) * m;
        x[i] = xv; mv[i] = m;
        lmax = fmaxf(lmax, xv);
    }
    // block max
    __shared__ float red[4];
#pragma unroll
    for (int o = 32; o > 0; o >>= 1) lmax = fmaxf(lmax, __shfl_down(lmax, o, 64));
    const int lane = t & 63, w = t >> 6;
    if (lane == 0) red[w] = lmax;
    __syncthreads();
    const float rmax = fmaxf(fmaxf(red[0], red[1]), fmaxf(red[2], red[3]));
    __syncthreads();

    float lsum = 0.f;
#pragma unroll
    for (int i = 0; i < 4; ++i) {
        float e = expf(x[i] - rmax) * mv[i];
        x[i] = e;
        lsum += e;
    }
#pragma unroll
    for (int o = 32; o > 0; o >>= 1) lsum += __shfl_down(lsum, o, 64);
    if (lane == 0) red[w] = lsum;
    __syncthreads();
    const float rsum = red[0] + red[1] + red[2] + red[3];
    const float inv = 1.0f / (rsum + 1e-6f);
#pragma unroll
    for (int i = 0; i < 4; ++i) row[t + i * 256] = x[i] * inv;
}

// ---- fc_out + fc_b + residual -> LayerNorm -> out ----
__global__ __launch_bounds__(256) void ln_kernel(const float* __restrict__ gout,
                                                 const float* __restrict__ qin,
                                                 const float* __restrict__ fc_b,
                                                 const float* __restrict__ ln_g,
                                                 const float* __restrict__ ln_b,
                                                 float* __restrict__ out)
{
    const int row = blockIdx.x;
    const int t = threadIdx.x;
    const size_t idx = (size_t)row * Dsz + t;
    const float val = gout[idx] + fc_b[t] + qin[idx];

    __shared__ float red[4];
    float s = val;
#pragma unroll
    for (int o = 32; o > 0; o >>= 1) s += __shfl_down(s, o, 64);
    const int lane = t & 63, w = t >> 6;
    if (lane == 0) red[w] = s;
    __syncthreads();
    const float mu = (red[0] + red[1] + red[2] + red[3]) * (1.0f / Dsz);
    __syncthreads();

    float d = val - mu;
    float s2 = d * d;
#pragma unroll
    for (int o = 32; o > 0; o >>= 1) s2 += __shfl_down(s2, o, 64);
    if (lane == 0) red[w] = s2;
    __syncthreads();
    const float var = (red[0] + red[1] + red[2] + red[3]) * (1.0f / Dsz);

    out[idx] = d * rsqrtf(var + 1e-5f) * ln_g[t] + ln_b[t];
}

extern "C" void kernel_launch(void* const* d_in, const int* in_sizes, int n_in,
                              void* d_out, int out_size, void* d_ws, size_t ws_size,
                              hipStream_t stream)
{
    const float* q    = (const float*)d_in[0];
    const int*   mask = (const int*)d_in[1];
    const float* k    = (const float*)d_in[2];
    const float* v    = (const float*)d_in[3];
    const float* w_qs = (const float*)d_in[4];
    const float* w_ks = (const float*)d_in[5];
    const float* w_vs = (const float*)d_in[6];
    const float* fc_w = (const float*)d_in[7];
    const float* fc_b = (const float*)d_in[8];
    const float* ln_g = (const float*)d_in[9];
    const float* ln_b = (const float*)d_in[10];

    float* out  = (float*)d_out;                       // [B,L,D] = 1,048,576 floats
    float* attn = (float*)d_out + (size_t)NROWS * Dsz; // [H*B,L,L] = 33,554,432 floats

    // Workspace layout (floats)
    float* ws   = (float*)d_ws;
    float* qh    = ws;                            // [4096, 2048]
    float* kh    = qh + (size_t)NROWS * HD;       // [4096, 2048]
    float* vh    = kh + (size_t)NROWS * HD;       // [4096, 2048]
    float* attnv = vh + (size_t)NROWS * HD;       // [4096, 2048]
    float* fcout = attnv + (size_t)NROWS * HD;    // [4096, 256]

    dim3 blk(256);

    // 1) Projections: [4096,256] @ [2048,256]^T -> [4096,2048]
    {
        dim3 grid(NROWS / BM, HD / BN, 1);
        gemm_tile<true><<<grid, blk, 0, stream>>>(q, w_qs, qh, NROWS, HD, Dsz,
            Dsz, Dsz, HD, 1, 0, 0, 0, 0, 0, 0, 1.0f);
        gemm_tile<true><<<grid, blk, 0, stream>>>(k, w_ks, kh, NROWS, HD, Dsz,
            Dsz, Dsz, HD, 1, 0, 0, 0, 0, 0, 0, 1.0f);
        gemm_tile<true><<<grid, blk, 0, stream>>>(v, w_vs, vh, NROWS, HD, Dsz,
            Dsz, Dsz, HD, 1, 0, 0, 0, 0, 0, 0, 1.0f);
    }

    // 2) Scores: per z=h*B+b: qh[b,:,h,:] @ kh[b,:,h,:]^T * (1/16) -> attn[z]
    {
        dim3 grid(Lsz / BM, Lsz / BN, Hsz * Bsz);
        gemm_tile<true><<<grid, blk, 0, stream>>>(qh, kh, attn, Lsz, Lsz, Dsz,
            HD, HD, Lsz, Bsz,
            /*sA1*/ Dsz, /*sA2*/ (long long)Lsz * HD,
            /*sB1*/ Dsz, /*sB2*/ (long long)Lsz * HD,
            /*sC1*/ (long long)Bsz * Lsz * Lsz, /*sC2*/ (long long)Lsz * Lsz,
            INV_TEMP);
    }

    // 3) Masked softmax in place
    softmax_kernel<<<dim3(Hsz * Bsz * Lsz), blk, 0, stream>>>(attn, mask);

    // 4) attn @ V: per z: [1024,1024] @ [1024(stride HD),256] -> attnv[b,:,h*D..]
    {
        dim3 grid(Lsz / BM, Dsz / BN, Hsz * Bsz);
        gemm_tile<false><<<grid, blk, 0, stream>>>(attn, vh, attnv, Lsz, Dsz, Lsz,
            Lsz, HD, HD, Bsz,
            /*sA1*/ (long long)Bsz * Lsz * Lsz, /*sA2*/ (long long)Lsz * Lsz,
            /*sB1*/ Dsz, /*sB2*/ (long long)Lsz * HD,
            /*sC1*/ Dsz, /*sC2*/ (long long)Lsz * HD,
            1.0f);
    }

    // 5) fc: [4096,2048] @ [256,2048]^T -> fcout [4096,256]
    {
        dim3 grid(NROWS / BM, Dsz / BN, 1);
        gemm_tile<true><<<grid, blk, 0, stream>>>(attnv, fc_w, fcout, NROWS, Dsz, HD,
            HD, HD, Dsz, 1, 0, 0, 0, 0, 0, 0, 1.0f);
    }

    // 6) bias + residual + LayerNorm
    ln_kernel<<<dim3(NROWS), blk, 0, stream>>>(fcout, q, fc_b, ln_g, ln_b, out);
}

// Round 2
// 398.492 us; speedup vs baseline: 2.4787x; 2.4787x over previous
//
#include <hip/hip_runtime.h>
#include <cstdint>
#include <math.h>

// Problem constants
#define Bsz 4
#define Lsz 1024
#define Dsz 256
#define Hsz 8
#define HD  2048          // H*D
#define NROWS (Bsz*Lsz)   // 4096
#define INV_TEMP 0.0625f  // 1/sqrt(256)

// MFMA GEMM tile params
#define TM 128
#define TN 128
#define TK 32

typedef __attribute__((ext_vector_type(8))) short bf16x8;
typedef __attribute__((ext_vector_type(4))) float f32x4;

__device__ inline unsigned short f2bf(float f) {
    union { float f; unsigned u; } x; x.f = f;
    unsigned r = x.u + 0x7fffu + ((x.u >> 16) & 1u);
    return (unsigned short)(r >> 16);
}

#define GBL(p) ((const __attribute__((address_space(1))) unsigned int*)(p))
#define LDS(p) ((__attribute__((address_space(3))) unsigned int*)(p))

// C = alpha * A @ B^T.  A [M,K] bf16(ushort) lda; Bm [N,K] bf16 ldb; C [M,N] OutT ldc.
// 2-level batch: z -> i1 = z/inner, i2 = z%inner.
template <typename OutT>
__global__ __launch_bounds__(256) void gemm_bt_mfma(
    const unsigned short* __restrict__ A, const unsigned short* __restrict__ Bm,
    OutT* __restrict__ C,
    int K, int lda, int ldb, int ldc,
    int inner,
    long long sA1, long long sA2, long long sB1, long long sB2,
    long long sC1, long long sC2, float alpha)
{
    const int z  = blockIdx.z;
    const int i1 = z / inner;
    const int i2 = z % inner;
    A  += (size_t)i1 * sA1 + (size_t)i2 * sA2;
    Bm += (size_t)i1 * sB1 + (size_t)i2 * sB2;
    C  += (size_t)i1 * sC1 + (size_t)i2 * sC2;

    __shared__ unsigned short As[TM * TK];  // [128][32] row-major, k contiguous
    __shared__ unsigned short Bs[TN * TK];

    const int t    = threadIdx.x;
    const int lane = t & 63;
    const int w    = t >> 6;
    const int wm   = w & 1;       // wave quadrant
    const int wn   = w >> 1;
    const int m0   = blockIdx.x * TM;
    const int n0   = blockIdx.y * TN;

    // staging: thread t loads 16B (8 bf16): row = t>>2 (+64 on pass 1), k-chunk = (t&3)*8
    const int sr = t >> 2;
    const int sc = (t & 3) * 8;
    const unsigned short* gA0 = A  + (size_t)(m0 + sr) * lda + sc;
    const unsigned short* gA1 = A  + (size_t)(m0 + 64 + sr) * lda + sc;
    const unsigned short* gB0 = Bm + (size_t)(n0 + sr) * ldb + sc;
    const unsigned short* gB1 = Bm + (size_t)(n0 + 64 + sr) * ldb + sc;
    unsigned short* lA0 = As + t * 8;         // byte offset t*16
    unsigned short* lA1 = As + 64 * TK + t * 8;
    unsigned short* lB0 = Bs + t * 8;
    unsigned short* lB1 = Bs + 64 * TK + t * 8;

    // fragment read addressing: lane&15 -> row within 16-tile, (lane>>4)*8 -> k offset
    const int fr = lane & 15;
    const int fk = (lane >> 4) * 8;
    const unsigned short* pA = As + (size_t)(wm * 64 + fr) * TK + fk;
    const unsigned short* pB = Bs + (size_t)(wn * 64 + fr) * TK + fk;

    f32x4 acc[4][4];
#pragma unroll
    for (int i = 0; i < 4; ++i)
#pragma unroll
        for (int j = 0; j < 4; ++j) acc[i][j] = (f32x4){0.f, 0.f, 0.f, 0.f};

    for (int k0 = 0; k0 < K; k0 += TK) {
        __builtin_amdgcn_global_load_lds(GBL(gA0 + k0), LDS(lA0), 16, 0, 0);
        __builtin_amdgcn_global_load_lds(GBL(gA1 + k0), LDS(lA1), 16, 0, 0);
        __builtin_amdgcn_global_load_lds(GBL(gB0 + k0), LDS(lB0), 16, 0, 0);
        __builtin_amdgcn_global_load_lds(GBL(gB1 + k0), LDS(lB1), 16, 0, 0);
        __syncthreads();

        bf16x8 a[4], b[4];
#pragma unroll
        for (int i = 0; i < 4; ++i) a[i] = *(const bf16x8*)(pA + i * 16 * TK);
#pragma unroll
        for (int j = 0; j < 4; ++j) b[j] = *(const bf16x8*)(pB + j * 16 * TK);
#pragma unroll
        for (int i = 0; i < 4; ++i)
#pragma unroll
            for (int j = 0; j < 4; ++j)
                acc[i][j] = __builtin_amdgcn_mfma_f32_16x16x32_bf16(a[i], b[j], acc[i][j], 0, 0, 0);
        __syncthreads();
    }

    // epilogue: C/D layout col = lane&15, row = (lane>>4)*4 + reg
    const int er = (lane >> 4) * 4;
    const int ec = lane & 15;
#pragma unroll
    for (int i = 0; i < 4; ++i) {
        const int mb = m0 + wm * 64 + i * 16 + er;
#pragma unroll
        for (int j = 0; j < 4; ++j) {
            const int n = n0 + wn * 64 + j * 16 + ec;
#pragma unroll
            for (int r = 0; r < 4; ++r) {
                float vv = acc[i][j][r] * alpha;
                if constexpr (sizeof(OutT) == 4)
                    C[(size_t)(mb + r) * ldc + n] = (OutT)vv;
                else
                    ((unsigned short*)C)[(size_t)(mb + r) * ldc + n] = f2bf(vv);
            }
        }
    }
}

// ---- fused fp32->bf16 cast of all GEMM inputs ----
// q,k,v: 1,048,576 elems each; w_qs,w_ks,w_vs,fc_w: 524,288 each. 4 elems/thread.
__global__ __launch_bounds__(256) void cast_all(
    const float* __restrict__ q, const float* __restrict__ k, const float* __restrict__ v,
    const float* __restrict__ wq, const float* __restrict__ wk, const float* __restrict__ wv,
    const float* __restrict__ fw,
    unsigned short* __restrict__ qb, unsigned short* __restrict__ kb, unsigned short* __restrict__ vb,
    unsigned short* __restrict__ wqb, unsigned short* __restrict__ wkb, unsigned short* __restrict__ wvb,
    unsigned short* __restrict__ fwb)
{
    const int gid = blockIdx.x * 256 + threadIdx.x;
    const int NQ = 262144;   // 1048576/4
    const int NW = 131072;   // 524288/4
    const float* src; unsigned short* dst; int off;
    if      (gid < NQ)            { src = q;  dst = qb;  off = gid; }
    else if (gid < 2 * NQ)        { src = k;  dst = kb;  off = gid - NQ; }
    else if (gid < 3 * NQ)        { src = v;  dst = vb;  off = gid - 2 * NQ; }
    else if (gid < 3 * NQ + NW)   { src = wq; dst = wqb; off = gid - 3 * NQ; }
    else if (gid < 3 * NQ + 2*NW) { src = wk; dst = wkb; off = gid - 3 * NQ - NW; }
    else if (gid < 3 * NQ + 3*NW) { src = wv; dst = wvb; off = gid - 3 * NQ - 2 * NW; }
    else                          { src = fw; dst = fwb; off = gid - 3 * NQ - 3 * NW; }
    float4 f = ((const float4*)src)[off];
    ushort4 o;
    o.x = f2bf(f.x); o.y = f2bf(f.y); o.z = f2bf(f.z); o.w = f2bf(f.w);
    ((ushort4*)dst)[off] = o;
}

// ---- masked softmax, in-place fp32 on attn rows [H*B, L, L]; also emits bf16 copy ----
__global__ __launch_bounds__(256) void softmax_kernel(float* __restrict__ attn,
                                                      unsigned short* __restrict__ attn_bf,
                                                      const int* __restrict__ mask)
{
    const int r  = blockIdx.x;            // (h*B + b)*L + q
    const int q  = r & (Lsz - 1);
    const int hb = r >> 10;               // h*B + b
    const int b  = hb & (Bsz - 1);
    float* row = attn + (size_t)r * Lsz;
    unsigned short* row_bf = attn_bf + (size_t)r * Lsz;
    const int* mrow = mask + ((size_t)(b * Lsz + q)) * Lsz;

    const int t = threadIdx.x;
    float x[4], mv[4];
    float lmax = -1e30f;
#pragma unroll
    for (int i = 0; i < 4; ++i) {
        const int idx = t + i * 256;
        float xv = row[idx];
        float m  = (float)mrow[idx];
        xv = fminf(fmaxf(xv, -15.f), 15.f) * m;
        x[i] = xv; mv[i] = m;
        lmax = fmaxf(lmax, xv);
    }
    __shared__ float red[4];
#pragma unroll
    for (int o = 32; o > 0; o >>= 1) lmax = fmaxf(lmax, __shfl_down(lmax, o, 64));
    const int lane = t & 63, w = t >> 6;
    if (lane == 0) red[w] = lmax;
    __syncthreads();
    const float rmax = fmaxf(fmaxf(red[0], red[1]), fmaxf(red[2], red[3]));
    __syncthreads();

    float lsum = 0.f;
#pragma unroll
    for (int i = 0; i < 4; ++i) {
        float e = expf(x[i] - rmax) * mv[i];
        x[i] = e;
        lsum += e;
    }
#pragma unroll
    for (int o = 32; o > 0; o >>= 1) lsum += __shfl_down(lsum, o, 64);
    if (lane == 0) red[w] = lsum;
    __syncthreads();
    const float rsum = red[0] + red[1] + red[2] + red[3];
    const float inv = 1.0f / (rsum + 1e-6f);
#pragma unroll
    for (int i = 0; i < 4; ++i) {
        const float p = x[i] * inv;
        row[t + i * 256] = p;
        row_bf[t + i * 256] = f2bf(p);
    }
}

// ---- fc_out + fc_b + residual -> LayerNorm -> out ----
__global__ __launch_bounds__(256) void ln_kernel(const float* __restrict__ gout,
                                                 const float* __restrict__ qin,
                                                 const float* __restrict__ fc_b,
                                                 const float* __restrict__ ln_g,
                                                 const float* __restrict__ ln_b,
                                                 float* __restrict__ out)
{
    const int row = blockIdx.x;
    const int t = threadIdx.x;
    const size_t idx = (size_t)row * Dsz + t;
    const float val = gout[idx] + fc_b[t] + qin[idx];

    __shared__ float red[4];
    float s = val;
#pragma unroll
    for (int o = 32; o > 0; o >>= 1) s += __shfl_down(s, o, 64);
    const int lane = t & 63, w = t >> 6;
    if (lane == 0) red[w] = s;
    __syncthreads();
    const float mu = (red[0] + red[1] + red[2] + red[3]) * (1.0f / Dsz);
    __syncthreads();

    float d = val - mu;
    float s2 = d * d;
#pragma unroll
    for (int o = 32; o > 0; o >>= 1) s2 += __shfl_down(s2, o, 64);
    if (lane == 0) red[w] = s2;
    __syncthreads();
    const float var = (red[0] + red[1] + red[2] + red[3]) * (1.0f / Dsz);

    out[idx] = d * rsqrtf(var + 1e-5f) * ln_g[t] + ln_b[t];
}

extern "C" void kernel_launch(void* const* d_in, const int* in_sizes, int n_in,
                              void* d_out, int out_size, void* d_ws, size_t ws_size,
                              hipStream_t stream)
{
    const float* q    = (const float*)d_in[0];
    const int*   mask = (const int*)d_in[1];
    const float* k    = (const float*)d_in[2];
    const float* v    = (const float*)d_in[3];
    const float* w_qs = (const float*)d_in[4];
    const float* w_ks = (const float*)d_in[5];
    const float* w_vs = (const float*)d_in[6];
    const float* fc_w = (const float*)d_in[7];
    const float* fc_b = (const float*)d_in[8];
    const float* ln_g = (const float*)d_in[9];
    const float* ln_b = (const float*)d_in[10];

    float* out  = (float*)d_out;                       // [B,L,D]
    float* attn = (float*)d_out + (size_t)NROWS * Dsz; // [H*B,L,L] fp32

    // Workspace layout (ushort elements).
    // Region X (first 33,554,432 ushort = 67.1 MB) hosts qh,kh,casts early; reused as attn_bf.
    unsigned short* wsu = (unsigned short*)d_ws;
    unsigned short* qh      = wsu;                                   // [4096,2048]
    unsigned short* kh      = qh + (size_t)NROWS * HD;               // [4096,2048]
    unsigned short* q_bf    = kh + (size_t)NROWS * HD;               // [4096,256]
    unsigned short* k_bf    = q_bf + (size_t)NROWS * Dsz;
    unsigned short* v_bf    = k_bf + (size_t)NROWS * Dsz;
    unsigned short* wq_bf   = v_bf + (size_t)NROWS * Dsz;            // [2048,256]
    unsigned short* wk_bf   = wq_bf + (size_t)HD * Dsz;
    unsigned short* wv_bf   = wk_bf + (size_t)HD * Dsz;
    unsigned short* attn_bf = wsu;                                   // [32,1024,1024] (reuse X)
    unsigned short* regionX_end = wsu + (size_t)32 * Lsz * Lsz;
    unsigned short* vt      = regionX_end;                           // [B,2048,1024]
    unsigned short* attnv   = vt + (size_t)Bsz * HD * Lsz;           // [4096,2048]
    unsigned short* fcw_bf  = attnv + (size_t)NROWS * HD;            // [256,2048]
    float*          fcout   = (float*)(fcw_bf + (size_t)Dsz * HD);   // [4096,256]

    dim3 blk(256);

    // 0) cast everything to bf16
    cast_all<<<dim3(5120), blk, 0, stream>>>(q, k, v, w_qs, w_ks, w_vs, fc_w,
                                             q_bf, k_bf, v_bf, wq_bf, wk_bf, wv_bf, fcw_bf);

    // 1) qh = q_bf @ w_qs^T, kh = k_bf @ w_ks^T : [4096,2048] bf16
    {
        dim3 grid(NROWS / TM, HD / TN, 1);
        gemm_bt_mfma<unsigned short><<<grid, blk, 0, stream>>>(q_bf, wq_bf, qh,
            Dsz, Dsz, Dsz, HD, 1, 0, 0, 0, 0, 0, 0, 1.0f);
        gemm_bt_mfma<unsigned short><<<grid, blk, 0, stream>>>(k_bf, wk_bf, kh,
            Dsz, Dsz, Dsz, HD, 1, 0, 0, 0, 0, 0, 0, 1.0f);
    }

    // 2) vt[b] = w_vs @ v_b^T : [2048,1024] per b (V projection, pre-transposed)
    {
        dim3 grid(HD / TM, Lsz / TN, Bsz);
        gemm_bt_mfma<unsigned short><<<grid, blk, 0, stream>>>(wv_bf, v_bf, vt,
            Dsz, Dsz, Dsz, Lsz, 1,
            /*sA1*/ 0, /*sA2*/ 0,
            /*sB1*/ (long long)Lsz * Dsz, /*sB2*/ 0,
            /*sC1*/ (long long)HD * Lsz, /*sC2*/ 0, 1.0f);
    }

    // 3) scores: per z=h*B+b: qh[b,:,h,:] @ kh[b,:,h,:]^T * (1/16) -> attn[z] fp32
    {
        dim3 grid(Lsz / TM, Lsz / TN, Hsz * Bsz);
        gemm_bt_mfma<float><<<grid, blk, 0, stream>>>(qh, kh, attn,
            Dsz, HD, HD, Lsz, Bsz,
            /*sA1*/ Dsz, /*sA2*/ (long long)Lsz * HD,
            /*sB1*/ Dsz, /*sB2*/ (long long)Lsz * HD,
            /*sC1*/ (long long)Bsz * Lsz * Lsz, /*sC2*/ (long long)Lsz * Lsz,
            INV_TEMP);
    }

    // 4) masked softmax (fp32 in d_out, bf16 copy into region X)
    softmax_kernel<<<dim3(Hsz * Bsz * Lsz), blk, 0, stream>>>(attn, attn_bf, mask);

    // 5) attn @ V: per z: attn_bf[z] [1024,1024] @ vt(z)^T -> attnv[b,:,h*D..] bf16
    {
        dim3 grid(Lsz / TM, Dsz / TN, Hsz * Bsz);
        gemm_bt_mfma<unsigned short><<<grid, blk, 0, stream>>>(attn_bf, vt, attnv,
            Lsz, Lsz, Lsz, HD, Bsz,
            /*sA1*/ (long long)Bsz * Lsz * Lsz, /*sA2*/ (long long)Lsz * Lsz,
            /*sB1*/ (long long)Dsz * Lsz, /*sB2*/ (long long)HD * Lsz,
            /*sC1*/ Dsz, /*sC2*/ (long long)Lsz * HD, 1.0f);
    }

    // 6) fc: attnv [4096,2048] @ fc_w^T [256,2048] -> fcout fp32
    {
        dim3 grid(NROWS / TM, Dsz / TN, 1);
        gemm_bt_mfma<float><<<grid, blk, 0, stream>>>(attnv, fcw_bf, fcout,
            HD, HD, HD, Dsz, 1, 0, 0, 0, 0, 0, 0, 1.0f);
    }

    // 7) bias + residual + LayerNorm
    ln_kernel<<<dim3(NROWS), blk, 0, stream>>>(fcout, q, fc_b, ln_g, ln_b, out);
}

// Round 3
// 362.227 us; speedup vs baseline: 2.7269x; 1.1001x over previous
//
#include <hip/hip_runtime.h>
#include <cstdint>
#include <math.h>

// Problem constants
#define Bsz 4
#define Lsz 1024
#define Dsz 256
#define Hsz 8
#define HD  2048          // H*D
#define NROWS (Bsz*Lsz)   // 4096
#define INV_TEMP 0.0625f  // 1/sqrt(256)

typedef __attribute__((ext_vector_type(8))) short bf16x8;
typedef __attribute__((ext_vector_type(4))) float f32x4;

__device__ inline unsigned short f2bf(float f) {
    union { float f; unsigned u; } x; x.f = f;
    unsigned r = x.u + 0x7fffu + ((x.u >> 16) & 1u);
    return (unsigned short)(r >> 16);
}
__device__ inline float bf2f(unsigned short u) {
    union { unsigned u; float f; } x; x.u = (unsigned)u << 16; return x.f;
}

#define GBL(p) ((const __attribute__((address_space(1))) unsigned int*)(p))
#define LDS(p) ((__attribute__((address_space(3))) unsigned int*)(p))

// C = alpha * A @ B^T.  A [M,K] bf16 lda; Bm [N,K] bf16 ldb.
// Tile 128x128, BK=64, XOR-swizzled LDS (2-way-conflict-free ds_read_b128).
// EPI: 0 = plain store (OutT float or bf16)
//      1 = scores: e = exp(clamp(acc*alpha)*m)*m, store bf16 (mask per-batch)
//      2 = pv: store bf16( acc * invs[row] )
template <typename OutT, int EPI>
__global__ __launch_bounds__(256) void gemm_bt(
    const unsigned short* __restrict__ A, const unsigned short* __restrict__ Bm,
    OutT* __restrict__ C,
    int K, int lda, int ldb, int ldc, int inner,
    long long sA1, long long sA2, long long sB1, long long sB2,
    long long sC1, long long sC2, float alpha,
    const int* __restrict__ mask, long long sM2,
    const float* __restrict__ invs, long long sI1, long long sI2)
{
    const int z  = blockIdx.z;
    const int i1 = z / inner;
    const int i2 = z % inner;
    A  += (size_t)i1 * sA1 + (size_t)i2 * sA2;
    Bm += (size_t)i1 * sB1 + (size_t)i2 * sB2;
    C  += (size_t)i1 * sC1 + (size_t)i2 * sC2;
    if (EPI == 1) mask += (size_t)i2 * sM2;
    if (EPI == 2) invs += (size_t)i1 * sI1 + (size_t)i2 * sI2;

    __shared__ unsigned short As[128 * 64];  // [row][64], chunk-swizzled
    __shared__ unsigned short Bs[128 * 64];

    const int t    = threadIdx.x;
    const int lane = t & 63;
    const int w    = t >> 6;
    const int wm   = w & 1;
    const int wn   = w >> 1;
    const int m0   = blockIdx.x * 128;
    const int n0   = blockIdx.y * 128;

    // staging: thread t stages row rr (+32 per pass), global k-chunk swizzled by row
    const int rr  = t >> 3;                       // 0..31
    const int gch = (((t & 7) ^ (rr & 7))) * 8;   // global chunk elems (swizzle)
    const unsigned short* gA = A  + (size_t)(m0 + rr) * lda + gch;
    const unsigned short* gB = Bm + (size_t)(n0 + rr) * ldb + gch;
    unsigned short* lA = As + t * 8;   // byte offset = t*16 (lane-linear per wave)
    unsigned short* lB = Bs + t * 8;

    const int fr = lane & 15;
    const int q  = lane >> 4;

    f32x4 acc[4][4];
#pragma unroll
    for (int i = 0; i < 4; ++i)
#pragma unroll
        for (int j = 0; j < 4; ++j) acc[i][j] = (f32x4){0.f, 0.f, 0.f, 0.f};

    for (int k0 = 0; k0 < K; k0 += 64) {
#pragma unroll
        for (int p = 0; p < 4; ++p) {
            __builtin_amdgcn_global_load_lds(GBL(gA + (size_t)p * 32 * lda + k0), LDS(lA + p * 2048), 16, 0, 0);
            __builtin_amdgcn_global_load_lds(GBL(gB + (size_t)p * 32 * ldb + k0), LDS(lB + p * 2048), 16, 0, 0);
        }
        __syncthreads();

#pragma unroll
        for (int s = 0; s < 2; ++s) {
            const int slot = ((s * 4 + q) ^ (fr & 7)) * 8;  // de-swizzle
            bf16x8 a[4], b[4];
#pragma unroll
            for (int i = 0; i < 4; ++i) a[i] = *(const bf16x8*)(As + (wm * 64 + i * 16 + fr) * 64 + slot);
#pragma unroll
            for (int j = 0; j < 4; ++j) b[j] = *(const bf16x8*)(Bs + (wn * 64 + j * 16 + fr) * 64 + slot);
#pragma unroll
            for (int i = 0; i < 4; ++i)
#pragma unroll
                for (int j = 0; j < 4; ++j)
                    acc[i][j] = __builtin_amdgcn_mfma_f32_16x16x32_bf16(a[i], b[j], acc[i][j], 0, 0, 0);
        }
        __syncthreads();
    }

    // epilogue: C/D layout col = lane&15, row = (lane>>4)*4 + reg
    const int er = q * 4;
    const int ec = fr;
#pragma unroll
    for (int i = 0; i < 4; ++i) {
        const int mb = m0 + wm * 64 + i * 16 + er;
#pragma unroll
        for (int j = 0; j < 4; ++j) {
            const int n = n0 + wn * 64 + j * 16 + ec;
#pragma unroll
            for (int r = 0; r < 4; ++r) {
                float vv = acc[i][j][r] * alpha;
                if (EPI == 0) {
                    if constexpr (sizeof(OutT) == 4)
                        C[(size_t)(mb + r) * ldc + n] = (OutT)vv;
                    else
                        ((unsigned short*)C)[(size_t)(mb + r) * ldc + n] = f2bf(vv);
                } else if (EPI == 1) {
                    const float m = (float)mask[(size_t)(mb + r) * Lsz + n];
                    vv = fminf(fmaxf(vv, -15.f), 15.f) * m;
                    vv = __expf(vv) * m;   // exp(0)*0 = 0 for masked
                    ((unsigned short*)C)[(size_t)(mb + r) * ldc + n] = f2bf(vv);
                } else {
                    vv *= invs[mb + r];
                    ((unsigned short*)C)[(size_t)(mb + r) * ldc + n] = f2bf(vv);
                }
            }
        }
    }
}

// ---- fp32->bf16 cast of all GEMM inputs ----
__global__ __launch_bounds__(256) void cast_all(
    const float* __restrict__ q, const float* __restrict__ k, const float* __restrict__ v,
    const float* __restrict__ wq, const float* __restrict__ wk, const float* __restrict__ wv,
    const float* __restrict__ fw,
    unsigned short* __restrict__ qb, unsigned short* __restrict__ kb, unsigned short* __restrict__ vb,
    unsigned short* __restrict__ wqb, unsigned short* __restrict__ wkb, unsigned short* __restrict__ wvb,
    unsigned short* __restrict__ fwb)
{
    const int gid = blockIdx.x * 256 + threadIdx.x;
    const int NQ = 262144;   // 1048576/4
    const int NW = 131072;   // 524288/4
    const float* src; unsigned short* dst; int off;
    if      (gid < NQ)            { src = q;  dst = qb;  off = gid; }
    else if (gid < 2 * NQ)        { src = k;  dst = kb;  off = gid - NQ; }
    else if (gid < 3 * NQ)        { src = v;  dst = vb;  off = gid - 2 * NQ; }
    else if (gid < 3 * NQ + NW)   { src = wq; dst = wqb; off = gid - 3 * NQ; }
    else if (gid < 3 * NQ + 2*NW) { src = wk; dst = wkb; off = gid - 3 * NQ - NW; }
    else if (gid < 3 * NQ + 3*NW) { src = wv; dst = wvb; off = gid - 3 * NQ - 2 * NW; }
    else                          { src = fw; dst = fwb; off = gid - 3 * NQ - 3 * NW; }
    float4 f = ((const float4*)src)[off];
    ushort4 o;
    o.x = f2bf(f.x); o.y = f2bf(f.y); o.z = f2bf(f.z); o.w = f2bf(f.w);
    ((ushort4*)dst)[off] = o;
}

// ---- normalize: read unnormalized e (bf16), write normalized fp32 attn + 1/(sum+eps) ----
__global__ __launch_bounds__(256) void norm_kernel(const unsigned short* __restrict__ e,
                                                   float* __restrict__ attn,
                                                   float* __restrict__ invsum)
{
    const int r = blockIdx.x;                  // global row in [0, 32768)
    const int t = threadIdx.x;
    const ushort4 u = ((const ushort4*)(e + (size_t)r * Lsz))[t];
    float x0 = bf2f(u.x), x1 = bf2f(u.y), x2 = bf2f(u.z), x3 = bf2f(u.w);
    float s = x0 + x1 + x2 + x3;

    __shared__ float red[4];
#pragma unroll
    for (int o = 32; o > 0; o >>= 1) s += __shfl_down(s, o, 64);
    const int lane = t & 63, w = t >> 6;
    if (lane == 0) red[w] = s;
    __syncthreads();
    const float inv = 1.0f / (red[0] + red[1] + red[2] + red[3] + 1e-6f);

    float4 o4; o4.x = x0 * inv; o4.y = x1 * inv; o4.z = x2 * inv; o4.w = x3 * inv;
    ((float4*)(attn + (size_t)r * Lsz))[t] = o4;
    if (t == 0) invsum[r] = inv;
}

// ---- fc_out + fc_b + residual -> LayerNorm -> out ----
__global__ __launch_bounds__(256) void ln_kernel(const float* __restrict__ gout,
                                                 const float* __restrict__ qin,
                                                 const float* __restrict__ fc_b,
                                                 const float* __restrict__ ln_g,
                                                 const float* __restrict__ ln_b,
                                                 float* __restrict__ out)
{
    const int row = blockIdx.x;
    const int t = threadIdx.x;
    const size_t idx = (size_t)row * Dsz + t;
    const float val = gout[idx] + fc_b[t] + qin[idx];

    __shared__ float red[4];
    float s = val;
#pragma unroll
    for (int o = 32; o > 0; o >>= 1) s += __shfl_down(s, o, 64);
    const int lane = t & 63, w = t >> 6;
    if (lane == 0) red[w] = s;
    __syncthreads();
    const float mu = (red[0] + red[1] + red[2] + red[3]) * (1.0f / Dsz);
    __syncthreads();

    float d = val - mu;
    float s2 = d * d;
#pragma unroll
    for (int o = 32; o > 0; o >>= 1) s2 += __shfl_down(s2, o, 64);
    if (lane == 0) red[w] = s2;
    __syncthreads();
    const float var = (red[0] + red[1] + red[2] + red[3]) * (1.0f / Dsz);

    out[idx] = d * rsqrtf(var + 1e-5f) * ln_g[t] + ln_b[t];
}

extern "C" void kernel_launch(void* const* d_in, const int* in_sizes, int n_in,
                              void* d_out, int out_size, void* d_ws, size_t ws_size,
                              hipStream_t stream)
{
    const float* q    = (const float*)d_in[0];
    const int*   mask = (const int*)d_in[1];
    const float* k    = (const float*)d_in[2];
    const float* v    = (const float*)d_in[3];
    const float* w_qs = (const float*)d_in[4];
    const float* w_ks = (const float*)d_in[5];
    const float* w_vs = (const float*)d_in[6];
    const float* fc_w = (const float*)d_in[7];
    const float* fc_b = (const float*)d_in[8];
    const float* ln_g = (const float*)d_in[9];
    const float* ln_b = (const float*)d_in[10];

    float* out  = (float*)d_out;                       // [B,L,D]
    float* attn = (float*)d_out + (size_t)NROWS * Dsz; // [H*B,L,L] fp32 normalized

    // Workspace layout (ushort units). No region reuse — all live ranges disjoint by order.
    unsigned short* wsu = (unsigned short*)d_ws;
    unsigned short* qh     = wsu;                                  // [4096,2048] (qh then kh contiguous)
    unsigned short* kh     = qh + (size_t)NROWS * HD;
    unsigned short* q_bf   = kh + (size_t)NROWS * HD;              // [4096,256] x3 contiguous
    unsigned short* k_bf   = q_bf + (size_t)NROWS * Dsz;
    unsigned short* v_bf   = k_bf + (size_t)NROWS * Dsz;
    unsigned short* wq_bf  = v_bf + (size_t)NROWS * Dsz;           // [2048,256] x3 contiguous
    unsigned short* wk_bf  = wq_bf + (size_t)HD * Dsz;
    unsigned short* wv_bf  = wk_bf + (size_t)HD * Dsz;
    unsigned short* vt     = wv_bf + (size_t)HD * Dsz;             // [B,2048,1024]
    unsigned short* attn_e = vt + (size_t)Bsz * HD * Lsz;          // [32,1024,1024] unnormalized e
    unsigned short* attnv  = attn_e + (size_t)32 * Lsz * Lsz;      // [4096,2048]
    unsigned short* fcw_bf = attnv + (size_t)NROWS * HD;           // [256,2048]
    float*          invsum = (float*)(fcw_bf + (size_t)Dsz * HD);  // [32768]
    float*          fcout  = invsum + 32768;                       // [4096,256]

    dim3 blk(256);

    // 0) cast everything to bf16
    cast_all<<<dim3(5120), blk, 0, stream>>>(q, k, v, w_qs, w_ks, w_vs, fc_w,
                                             q_bf, k_bf, v_bf, wq_bf, wk_bf, wv_bf, fcw_bf);

    // 1) q/k projections in one dispatch: z=0 -> qh, z=1 -> kh
    {
        dim3 grid(NROWS / 128, HD / 128, 2);
        gemm_bt<unsigned short, 0><<<grid, blk, 0, stream>>>(q_bf, wq_bf, qh,
            Dsz, Dsz, Dsz, HD, 2,
            0, (long long)NROWS * Dsz, 0, (long long)HD * Dsz, 0, (long long)NROWS * HD,
            1.0f, nullptr, 0, nullptr, 0, 0);
    }

    // 2) vt[b] = w_vs @ v_b^T : [2048,1024] per b
    {
        dim3 grid(HD / 128, Lsz / 128, Bsz);
        gemm_bt<unsigned short, 0><<<grid, blk, 0, stream>>>(wv_bf, v_bf, vt,
            Dsz, Dsz, Dsz, Lsz, 1,
            0, 0, (long long)Lsz * Dsz, 0, (long long)HD * Lsz, 0,
            1.0f, nullptr, 0, nullptr, 0, 0);
    }

    // 3) scores + clamp/mask/exp fused: attn_e[z] = exp(clamp(qh kh^T /16)*m)*m  (bf16, unnormalized)
    {
        dim3 grid(Lsz / 128, Lsz / 128, Hsz * Bsz);
        gemm_bt<unsigned short, 1><<<grid, blk, 0, stream>>>(qh, kh, attn_e,
            Dsz, HD, HD, Lsz, Bsz,
            Dsz, (long long)Lsz * HD, Dsz, (long long)Lsz * HD,
            (long long)Bsz * Lsz * Lsz, (long long)Lsz * Lsz,
            INV_TEMP, mask, (long long)Lsz * Lsz, nullptr, 0, 0);
    }

    // 4) normalize: fp32 attn output + per-row 1/(sum+eps)
    norm_kernel<<<dim3(32 * Lsz), blk, 0, stream>>>(attn_e, attn, invsum);

    // 5) pv: attnv = (e @ vt^T) * inv[row]  (bf16)
    {
        dim3 grid(Lsz / 128, Dsz / 128, Hsz * Bsz);
        gemm_bt<unsigned short, 2><<<grid, blk, 0, stream>>>(attn_e, vt, attnv,
            Lsz, Lsz, Lsz, HD, Bsz,
            (long long)Bsz * Lsz * Lsz, (long long)Lsz * Lsz,
            (long long)Dsz * Lsz, (long long)HD * Lsz,
            Dsz, (long long)Lsz * HD,
            1.0f, nullptr, 0, invsum, (long long)Bsz * Lsz, (long long)Lsz);
    }

    // 6) fc: attnv [4096,2048] @ fc_w^T [256,2048] -> fcout fp32
    {
        dim3 grid(NROWS / 128, Dsz / 128, 1);
        gemm_bt<float, 0><<<grid, blk, 0, stream>>>(attnv, fcw_bf, fcout,
            HD, HD, HD, Dsz, 1, 0, 0, 0, 0, 0, 0,
            1.0f, nullptr, 0, nullptr, 0, 0);
    }

    // 7) bias + residual + LayerNorm
    ln_kernel<<<dim3(NROWS), blk, 0, stream>>>(fcout, q, fc_b, ln_g, ln_b, out);
}

// Round 4
// 348.197 us; speedup vs baseline: 2.8367x; 1.0403x over previous
//
#include <hip/hip_runtime.h>
#include <cstdint>
#include <math.h>

// Problem constants
#define Bsz 4
#define Lsz 1024
#define Dsz 256
#define Hsz 8
#define HD  2048          // H*D
#define NROWS (Bsz*Lsz)   // 4096
#define INV_TEMP 0.0625f  // 1/sqrt(256)

typedef __attribute__((ext_vector_type(8))) short bf16x8;
typedef __attribute__((ext_vector_type(4))) float f32x4;

__device__ inline unsigned short f2bf(float f) {
    union { float f; unsigned u; } x; x.f = f;
    unsigned r = x.u + 0x7fffu + ((x.u >> 16) & 1u);
    return (unsigned short)(r >> 16);
}
__device__ inline float bf2f(unsigned short u) {
    union { unsigned u; float f; } x; x.u = (unsigned)u << 16; return x.f;
}

#define GBL(p) ((const __attribute__((address_space(1))) unsigned int*)(p))
#define LDS(p) ((__attribute__((address_space(3))) unsigned int*)(p))

// C = alpha * A @ B^T.  A [M,K] bf16 lda; Bm [N,K] bf16 ldb.
// Tile TMv x TNv (TNv=256), BK=64, XOR-swizzled LDS staging + ds_read_b128 frags.
// 4 waves as 2x2 quadrants of (TMv/2)x(TNv/2).
// EPI: 0 = plain store; 1 = scores (clamp*mask, exp*mask, bf16); 2 = pv (scale by invs[row], bf16)
template <int TMv, int TNv, typename OutT, int EPI, int MINW>
__global__ __launch_bounds__(256, MINW) void gemm_bt(
    const unsigned short* __restrict__ A, const unsigned short* __restrict__ Bm,
    OutT* __restrict__ C,
    int K, int lda, int ldb, int ldc, int inner,
    long long sA1, long long sA2, long long sB1, long long sB2,
    long long sC1, long long sC2, float alpha,
    const int* __restrict__ mask, long long sM2,
    const float* __restrict__ invs, long long sI1, long long sI2)
{
    constexpr int WMv = TMv / 2, WNv = TNv / 2;
    constexpr int IT = TMv / 32, JT = TNv / 32;
    constexpr int APASS = TMv / 32, NPASS = (TMv + TNv) / 32;

    const int z  = blockIdx.z;
    const int i1 = z / inner;
    const int i2 = z % inner;
    A  += (size_t)i1 * sA1 + (size_t)i2 * sA2;
    Bm += (size_t)i1 * sB1 + (size_t)i2 * sB2;
    C  += (size_t)i1 * sC1 + (size_t)i2 * sC2;
    if (EPI == 1) mask += (size_t)i2 * sM2;
    if (EPI == 2) invs += (size_t)i1 * sI1 + (size_t)i2 * sI2;

    __shared__ unsigned short S[(TMv + TNv) * 64];
    unsigned short* As = S;
    unsigned short* Bs = S + TMv * 64;

    const int t    = threadIdx.x;
    const int lane = t & 63;
    const int w    = t >> 6;
    const int wm   = w & 1;
    const int wn   = w >> 1;
    const int m0   = blockIdx.x * TMv;
    const int n0   = blockIdx.y * TNv;

    // staging: 32 rows per pass, 8 threads/row, 16B each; global chunk XOR-swizzled by row
    const int rA = t >> 3;
    const int ch = (((t & 7) ^ (rA & 7))) * 8;
    const unsigned short* gA = A  + (size_t)(m0 + rA) * lda + ch;
    const unsigned short* gB = Bm + (size_t)(n0 + rA) * ldb + ch;

    const int fr = lane & 15;
    const int q  = lane >> 4;

    f32x4 acc[IT][JT];
#pragma unroll
    for (int i = 0; i < IT; ++i)
#pragma unroll
        for (int j = 0; j < JT; ++j) acc[i][j] = (f32x4){0.f, 0.f, 0.f, 0.f};

    for (int k0 = 0; k0 < K; k0 += 64) {
#pragma unroll
        for (int p = 0; p < NPASS; ++p) {
            const unsigned short* src = (p < APASS)
                ? (gA + (size_t)p * 32 * lda + k0)
                : (gB + (size_t)(p - APASS) * 32 * ldb + k0);
            __builtin_amdgcn_global_load_lds(GBL(src), LDS(S + p * 2048 + t * 8), 16, 0, 0);
        }
        __syncthreads();

#pragma unroll
        for (int ks = 0; ks < 2; ++ks) {
            const int slot = ((ks * 4 + q) ^ (fr & 7)) * 8;  // de-swizzle
            bf16x8 a[IT], b[JT];
#pragma unroll
            for (int i = 0; i < IT; ++i)
                a[i] = *(const bf16x8*)(As + (wm * WMv + i * 16 + fr) * 64 + slot);
#pragma unroll
            for (int j = 0; j < JT; ++j)
                b[j] = *(const bf16x8*)(Bs + (wn * WNv + j * 16 + fr) * 64 + slot);
#pragma unroll
            for (int i = 0; i < IT; ++i)
#pragma unroll
                for (int j = 0; j < JT; ++j)
                    acc[i][j] = __builtin_amdgcn_mfma_f32_16x16x32_bf16(a[i], b[j], acc[i][j], 0, 0, 0);
        }
        __syncthreads();
    }

    // epilogue: C/D layout col = lane&15, row = (lane>>4)*4 + reg
#pragma unroll
    for (int i = 0; i < IT; ++i) {
#pragma unroll
        for (int r = 0; r < 4; ++r) {
            const int row = m0 + wm * WMv + i * 16 + q * 4 + r;
#pragma unroll
            for (int j = 0; j < JT; ++j) {
                const int col = n0 + wn * WNv + j * 16 + fr;
                float vv = acc[i][j][r] * alpha;
                if (EPI == 0) {
                    if constexpr (sizeof(OutT) == 4)
                        C[(size_t)row * ldc + col] = (OutT)vv;
                    else
                        ((unsigned short*)C)[(size_t)row * ldc + col] = f2bf(vv);
                } else if (EPI == 1) {
                    const float m = (float)mask[(size_t)row * Lsz + col];
                    vv = fminf(fmaxf(vv, -15.f), 15.f) * m;
                    vv = __expf(vv) * m;
                    ((unsigned short*)C)[(size_t)row * ldc + col] = f2bf(vv);
                } else {
                    vv *= invs[row];
                    ((unsigned short*)C)[(size_t)row * ldc + col] = f2bf(vv);
                }
            }
        }
    }
}

// ---- fp32->bf16 cast of all GEMM inputs ----
__global__ __launch_bounds__(256) void cast_all(
    const float* __restrict__ q, const float* __restrict__ k, const float* __restrict__ v,
    const float* __restrict__ wq, const float* __restrict__ wk, const float* __restrict__ wv,
    const float* __restrict__ fw,
    unsigned short* __restrict__ qb, unsigned short* __restrict__ kb, unsigned short* __restrict__ vb,
    unsigned short* __restrict__ wqb, unsigned short* __restrict__ wkb, unsigned short* __restrict__ wvb,
    unsigned short* __restrict__ fwb)
{
    const int gid = blockIdx.x * 256 + threadIdx.x;
    const int NQ = 262144;   // 1048576/4
    const int NW = 131072;   // 524288/4
    const float* src; unsigned short* dst; int off;
    if      (gid < NQ)            { src = q;  dst = qb;  off = gid; }
    else if (gid < 2 * NQ)        { src = k;  dst = kb;  off = gid - NQ; }
    else if (gid < 3 * NQ)        { src = v;  dst = vb;  off = gid - 2 * NQ; }
    else if (gid < 3 * NQ + NW)   { src = wq; dst = wqb; off = gid - 3 * NQ; }
    else if (gid < 3 * NQ + 2*NW) { src = wk; dst = wkb; off = gid - 3 * NQ - NW; }
    else if (gid < 3 * NQ + 3*NW) { src = wv; dst = wvb; off = gid - 3 * NQ - 2 * NW; }
    else                          { src = fw; dst = fwb; off = gid - 3 * NQ - 3 * NW; }
    float4 f = ((const float4*)src)[off];
    ushort4 o;
    o.x = f2bf(f.x); o.y = f2bf(f.y); o.z = f2bf(f.z); o.w = f2bf(f.w);
    ((ushort4*)dst)[off] = o;
}

// ---- normalize: wave per row, no barriers. read e bf16, write fp32 attn + invsum ----
__global__ __launch_bounds__(256) void norm_kernel(const unsigned short* __restrict__ e,
                                                   float* __restrict__ attn,
                                                   float* __restrict__ invsum)
{
    const int r    = blockIdx.x * 4 + (threadIdx.x >> 6);
    const int lane = threadIdx.x & 63;
    const unsigned short* rowp = e + (size_t)r * Lsz + lane * 16;

    union { uint4 v[2]; unsigned short u[16]; } buf;
    buf.v[0] = *(const uint4*)rowp;
    buf.v[1] = *(const uint4*)(rowp + 8);

    float f[16];
    float s = 0.f;
#pragma unroll
    for (int i = 0; i < 16; ++i) { f[i] = bf2f(buf.u[i]); s += f[i]; }
#pragma unroll
    for (int o = 1; o <= 32; o <<= 1) s += __shfl_xor(s, o, 64);
    const float inv = 1.0f / (s + 1e-6f);

    float* op = attn + (size_t)r * Lsz + lane * 16;
#pragma unroll
    for (int c = 0; c < 4; ++c) {
        float4 o4;
        o4.x = f[c * 4 + 0] * inv; o4.y = f[c * 4 + 1] * inv;
        o4.z = f[c * 4 + 2] * inv; o4.w = f[c * 4 + 3] * inv;
        *(float4*)(op + c * 4) = o4;
    }
    if (lane == 0) invsum[r] = inv;
}

// ---- sum 4 fc split-K partials + fc_b + residual -> LayerNorm -> out ----
__global__ __launch_bounds__(256) void ln_kernel(const float* __restrict__ gout,
                                                 const float* __restrict__ qin,
                                                 const float* __restrict__ fc_b,
                                                 const float* __restrict__ ln_g,
                                                 const float* __restrict__ ln_b,
                                                 float* __restrict__ out)
{
    const int row = blockIdx.x;
    const int t = threadIdx.x;
    const size_t idx = (size_t)row * Dsz + t;
    const size_t P = (size_t)NROWS * Dsz;
    const float val = gout[idx] + gout[idx + P] + gout[idx + 2 * P] + gout[idx + 3 * P]
                    + fc_b[t] + qin[idx];

    __shared__ float red[4];
    float s = val;
#pragma unroll
    for (int o = 32; o > 0; o >>= 1) s += __shfl_down(s, o, 64);
    const int lane = t & 63, w = t >> 6;
    if (lane == 0) red[w] = s;
    __syncthreads();
    const float mu = (red[0] + red[1] + red[2] + red[3]) * (1.0f / Dsz);
    __syncthreads();

    float d = val - mu;
    float s2 = d * d;
#pragma unroll
    for (int o = 32; o > 0; o >>= 1) s2 += __shfl_down(s2, o, 64);
    if (lane == 0) red[w] = s2;
    __syncthreads();
    const float var = (red[0] + red[1] + red[2] + red[3]) * (1.0f / Dsz);

    out[idx] = d * rsqrtf(var + 1e-5f) * ln_g[t] + ln_b[t];
}

extern "C" void kernel_launch(void* const* d_in, const int* in_sizes, int n_in,
                              void* d_out, int out_size, void* d_ws, size_t ws_size,
                              hipStream_t stream)
{
    const float* q    = (const float*)d_in[0];
    const int*   mask = (const int*)d_in[1];
    const float* k    = (const float*)d_in[2];
    const float* v    = (const float*)d_in[3];
    const float* w_qs = (const float*)d_in[4];
    const float* w_ks = (const float*)d_in[5];
    const float* w_vs = (const float*)d_in[6];
    const float* fc_w = (const float*)d_in[7];
    const float* fc_b = (const float*)d_in[8];
    const float* ln_g = (const float*)d_in[9];
    const float* ln_b = (const float*)d_in[10];

    float* out  = (float*)d_out;                       // [B,L,D]
    float* attn = (float*)d_out + (size_t)NROWS * Dsz; // [H*B,L,L] fp32 normalized

    // Workspace layout (ushort units)
    unsigned short* wsu = (unsigned short*)d_ws;
    unsigned short* qh     = wsu;                                  // [4096,2048]
    unsigned short* kh     = qh + (size_t)NROWS * HD;              // [4096,2048]
    unsigned short* q_bf   = kh + (size_t)NROWS * HD;              // [4096,256] x3
    unsigned short* k_bf   = q_bf + (size_t)NROWS * Dsz;
    unsigned short* v_bf   = k_bf + (size_t)NROWS * Dsz;
    unsigned short* wq_bf  = v_bf + (size_t)NROWS * Dsz;           // [2048,256] x3
    unsigned short* wk_bf  = wq_bf + (size_t)HD * Dsz;
    unsigned short* wv_bf  = wk_bf + (size_t)HD * Dsz;
    unsigned short* vt     = wv_bf + (size_t)HD * Dsz;             // [B,2048,1024]
    unsigned short* attn_e = vt + (size_t)Bsz * HD * Lsz;          // [32,1024,1024] unnormalized e
    unsigned short* attnv  = attn_e + (size_t)32 * Lsz * Lsz;      // [4096,2048]
    unsigned short* fcw_bf = attnv + (size_t)NROWS * HD;           // [256,2048]
    float*          invsum = (float*)(fcw_bf + (size_t)Dsz * HD);  // [32768]
    float*          fcout  = invsum + 32768;                       // [4,4096,256] split-K partials

    dim3 blk(256);

    // 0) cast everything to bf16
    cast_all<<<dim3(5120), blk, 0, stream>>>(q, k, v, w_qs, w_ks, w_vs, fc_w,
                                             q_bf, k_bf, v_bf, wq_bf, wk_bf, wv_bf, fcw_bf);

    // 1) q/k projections, one dispatch: z=0 -> qh, z=1 -> kh. 64x256 tile, grid 64x8x2.
    {
        dim3 grid(NROWS / 64, HD / 256, 2);
        gemm_bt<64, 256, unsigned short, 0, 3><<<grid, blk, 0, stream>>>(q_bf, wq_bf, qh,
            Dsz, Dsz, Dsz, HD, 2,
            0, (long long)NROWS * Dsz, 0, (long long)HD * Dsz, 0, (long long)NROWS * HD,
            1.0f, nullptr, 0, nullptr, 0, 0);
    }

    // 2) vt[b] = w_vs @ v_b^T : [2048,1024] per b. 64x256, grid 32x4x4.
    {
        dim3 grid(HD / 64, Lsz / 256, Bsz);
        gemm_bt<64, 256, unsigned short, 0, 3><<<grid, blk, 0, stream>>>(wv_bf, v_bf, vt,
            Dsz, Dsz, Dsz, Lsz, 1,
            0, 0, (long long)Lsz * Dsz, 0, (long long)HD * Lsz, 0,
            1.0f, nullptr, 0, nullptr, 0, 0);
    }

    // 3) scores + clamp/mask/exp: attn_e[z] = exp(clamp(qh kh^T /16)*m)*m (bf16). 128x256, grid 8x4x32.
    {
        dim3 grid(Lsz / 128, Lsz / 256, Hsz * Bsz);
        gemm_bt<128, 256, unsigned short, 1, 2><<<grid, blk, 0, stream>>>(qh, kh, attn_e,
            Dsz, HD, HD, Lsz, Bsz,
            Dsz, (long long)Lsz * HD, Dsz, (long long)Lsz * HD,
            (long long)Bsz * Lsz * Lsz, (long long)Lsz * Lsz,
            INV_TEMP, mask, (long long)Lsz * Lsz, nullptr, 0, 0);
    }

    // 4) normalize: fp32 attn output + per-row 1/(sum+eps). Wave per row.
    norm_kernel<<<dim3(32 * Lsz / 4), blk, 0, stream>>>(attn_e, attn, invsum);

    // 5) pv: attnv = (e @ vt^T) * inv[row]. 64x256 full-N tile, grid 16x1x32.
    {
        dim3 grid(Lsz / 64, Dsz / 256, Hsz * Bsz);
        gemm_bt<64, 256, unsigned short, 2, 3><<<grid, blk, 0, stream>>>(attn_e, vt, attnv,
            Lsz, Lsz, Lsz, HD, Bsz,
            (long long)Bsz * Lsz * Lsz, (long long)Lsz * Lsz,
            (long long)Dsz * Lsz, (long long)HD * Lsz,
            Dsz, (long long)Lsz * HD,
            1.0f, nullptr, 0, invsum, (long long)Bsz * Lsz, (long long)Lsz);
    }

    // 6) fc split-K x4: fcout[p] = attnv[:, p*512:+512] @ fc_w[:, p*512:+512]^T. 64x256, grid 64x1x4.
    {
        dim3 grid(NROWS / 64, Dsz / 256, 4);
        gemm_bt<64, 256, float, 0, 3><<<grid, blk, 0, stream>>>(attnv, fcw_bf, fcout,
            512, HD, HD, Dsz, 4,
            0, 512, 0, 512, 0, (long long)NROWS * Dsz,
            1.0f, nullptr, 0, nullptr, 0, 0);
    }

    // 7) sum partials + bias + residual + LayerNorm
    ln_kernel<<<dim3(NROWS), blk, 0, stream>>>(fcout, q, fc_b, ln_g, ln_b, out);
}